// Round 7
// baseline (289.014 us; speedup 1.0000x reference)
//
#include <hip/hip_runtime.h>
#include <hip/hip_bf16.h>

typedef __attribute__((ext_vector_type(4))) float f32x4;
typedef __attribute__((ext_vector_type(8))) short short8;
typedef __attribute__((ext_vector_type(8))) __bf16 bf16x8;

#define NDIM 172
#define EDIM 172
#define TDIM 100
#define KCAT 444   // 172+172+100
#define QDIM 272   // 172+100
#define ODIM 128
#define ZDIM 256
#define NNBR 32
#define BPB 2      // batch rows per fused block (M = 64)
#define NPH 14     // 14 K=32 phases (448 padded K)
#define LN_EPS 1e-5f

// Z_lds byte offset with XOR bank-swizzle (row stride 512 B)
#define ZB(r,c) ((((r) * 512) + ((c) * 2)) ^ (((r) & 7) << 4))

__device__ __forceinline__ unsigned short f2bf(float f) {
    unsigned u = __builtin_bit_cast(unsigned, f);
    u += 0x7fffu + ((u >> 16) & 1u);
    return (unsigned short)(u >> 16);
}
__device__ __forceinline__ float bf2f(unsigned short h) {
    unsigned u = ((unsigned)h) << 16;
    return __builtin_bit_cast(float, u);
}
// native f32->bf16 (compiler emits v_cvt_pk_bf16_f32 pairs)
__device__ __forceinline__ bf16x8 cvt8(float4 a, float4 b) {
    bf16x8 r;
    r[0] = (__bf16)a.x; r[1] = (__bf16)a.y; r[2] = (__bf16)a.z; r[3] = (__bf16)a.w;
    r[4] = (__bf16)b.x; r[5] = (__bf16)b.y; r[6] = (__bf16)b.z; r[7] = (__bf16)b.w;
    return r;
}

// ---- prep: wfrag = Wkv bf16 in MFMA B-fragment order:
// [phase 0..13][n16 0..15][lane 0..63][8 bf16]; lane l <-> row=n16*16+(l&15),
// k = phase*32 + (l>>4)*8 + e. Each (phase,n16) chunk = 1 KB, loaded by one
// wave as a coalesced dwordx4. Also wqT bf16[272][128], woT bf16[128][128].
#define WFRAG_N (NPH * 8192)        // 114688 shorts
#define WQT_N (QDIM * ODIM)         // 34816
#define WOT_N (ODIM * ODIM)         // 16384
__global__ void prep_pack(const float* __restrict__ Wkv, const float* __restrict__ Wq,
                          const float* __restrict__ Wo,
                          unsigned short* __restrict__ wfrag,
                          unsigned short* __restrict__ wqT,
                          unsigned short* __restrict__ woT) {
    int idx = blockIdx.x * 256 + threadIdx.x;
    if (idx < WFRAG_N) {
        int phase = idx >> 13;           // 8192 shorts per phase
        int r = idx & 8191;
        int n16 = r >> 9;                // 512 shorts per n16 chunk
        int q = r & 511;
        int l = q >> 3, e = q & 7;
        int row = n16 * 16 + (l & 15);
        int k = phase * 32 + ((l >> 4) << 3) + e;
        wfrag[idx] = f2bf(k < KCAT ? Wkv[row * KCAT + k] : 0.f);
    } else if (idx < WFRAG_N + WQT_N) {
        int j = idx - WFRAG_N;
        int k = j >> 7, c = j & 127;
        wqT[j] = f2bf(Wq[c * QDIM + k]);
    } else if (idx < WFRAG_N + WQT_N + WOT_N) {
        int j = idx - WFRAG_N - WQT_N;
        int k = j >> 7, c = j & 127;
        woT[j] = f2bf(Wo[c * ODIM + k]);
    }
}

// ---- Q projection: Q[B,128] = concat(node,time) @ Wq^T + bq  (coalesced via wqT)
__global__ __launch_bounds__(256) void q_proj(
    const float* __restrict__ node_feat, const float* __restrict__ time_feat,
    const unsigned short* __restrict__ wqT, const float* __restrict__ bq,
    float* __restrict__ Qbuf) {
    __shared__ float x[8][QDIM];
    const int tid = threadIdx.x;
    const long b0 = (long)blockIdx.x * 8;
    for (int g = tid; g < 8 * QDIM; g += 256) {
        int r = g / QDIM, k = g - r * QDIM;
        x[r][k] = (k < NDIM) ? node_feat[(b0 + r) * NDIM + k]
                             : time_feat[(b0 + r) * TDIM + (k - NDIM)];
    }
    __syncthreads();
    const int c = tid & 127;
    const int rb = (tid >> 7) * 4;
    float s0 = bq[c], s1 = s0, s2 = s0, s3 = s0;
    #pragma unroll 8
    for (int k = 0; k < QDIM; k++) {
        float w = bf2f(wqT[k * 128 + c]);
        s0 += x[rb + 0][k] * w;
        s1 += x[rb + 1][k] * w;
        s2 += x[rb + 2][k] * w;
        s3 += x[rb + 3][k] * w;
    }
    Qbuf[(b0 + rb + 0) * 128 + c] = s0;
    Qbuf[(b0 + rb + 1) * 128 + c] = s1;
    Qbuf[(b0 + rb + 2) * 128 + c] = s2;
    Qbuf[(b0 + rb + 3) * 128 + c] = s3;
}

__global__ __launch_bounds__(512, 4) void ta_fused(
    const float* __restrict__ edge_feat, const float* __restrict__ nbr_node,
    const float* __restrict__ nbr_time, const int* __restrict__ nbr_mask,
    const float* __restrict__ Qbuf,
    const unsigned short* __restrict__ wfrag, const float* __restrict__ bkv,
    const unsigned short* __restrict__ woT, const float* __restrict__ bo,
    const float* __restrict__ gamma, const float* __restrict__ beta,
    float* __restrict__ out)
{
    __shared__ __align__(16) unsigned char zsm[32768];  // Z bf16 [64][256] ZB-swizzled
    __shared__ float qres[BPB][ODIM];
    __shared__ float Pband[BPB][2][NNBR];
    __shared__ float Obuf[BPB][ODIM];
    __shared__ float red[4][2];

    const int tid  = threadIdx.x;
    const int lane = tid & 63;
    const int wid  = tid >> 6;
    const int b0   = blockIdx.x * BPB;
    const int wm   = wid >> 2;           // 0..1 : 32-row band
    const int wn   = wid & 3;            // 0..3 : 64-col band
    const int koff = (lane >> 4) << 3;   // 0,8,16,24 : k-octet within K=32

    // ---- stage precomputed Q rows (coalesced)
    if (tid < BPB * ODIM) {
        int b = tid >> 7, c = tid & 127;
        qres[b][c] = Qbuf[(long)(b0 + b) * ODIM + c];
    }

    // ---- per-lane A fragment row pointers (koff folded in)
    const float *pN[2], *pE[2], *pT[2];
    #pragma unroll
    for (int m = 0; m < 2; m++) {
        int rr = wm * 32 + m * 16 + (lane & 15);
        long rg = (long)(b0 + (rr >> 5)) * NNBR + (rr & 31);
        pN[m] = nbr_node  + rg * NDIM + koff;
        pE[m] = edge_feat + rg * EDIM + koff;
        pT[m] = nbr_time  + rg * TDIM + koff;
    }
    const unsigned short* wp = wfrag + (size_t)(wn * 4) * 512 + lane * 8;

    f32x4 acc[2][4];
    #pragma unroll
    for (int m = 0; m < 2; m++)
        #pragma unroll
        for (int n = 0; n < 4; n++) acc[m][n] = (f32x4){0.f, 0.f, 0.f, 0.f};

    float4 av[2][2][2];   // [buf][m][half] : A fp32 in flight (double-buffered)
    uint4  wv[4];         // W frags for current phase

    auto issueA = [&](int p, int s) {
        const int kb = p * 32;
        #pragma unroll
        for (int m = 0; m < 2; m++) {
            if (kb + 32 <= NDIM) {                              // pure node (p 0..4)
                av[s][m][0] = *(const float4*)(pN[m] + kb);
                av[s][m][1] = *(const float4*)(pN[m] + kb + 4);
            } else if (kb >= NDIM && kb + 32 <= NDIM + EDIM) {  // pure edge (p 6..9)
                av[s][m][0] = *(const float4*)(pE[m] + (kb - NDIM));
                av[s][m][1] = *(const float4*)(pE[m] + (kb - NDIM) + 4);
            } else if (kb >= NDIM + EDIM && kb + 32 <= KCAT) {  // pure time (p 11..12)
                av[s][m][0] = *(const float4*)(pT[m] + (kb - NDIM - EDIM));
                av[s][m][1] = *(const float4*)(pT[m] + (kb - NDIM - EDIM) + 4);
            } else {                                            // mixed (p 5,10,13)
                #pragma unroll
                for (int h = 0; h < 2; h++) {
                    int k = kb + koff + h * 4;
                    const float* p4;
                    if (k < NDIM)             p4 = pN[m] + kb + h * 4;
                    else if (k < NDIM + EDIM) p4 = pE[m] + (kb - NDIM) + h * 4;
                    else                      p4 = pT[m] + (kb - NDIM - EDIM) + h * 4;
                    float4 v = make_float4(0.f, 0.f, 0.f, 0.f);
                    if (k < KCAT) v = *(const float4*)p4;
                    av[s][m][h] = v;
                }
            }
        }
    };
    auto issueW = [&](int p) {
        #pragma unroll
        for (int n = 0; n < 4; n++)
            wv[n] = *(const uint4*)(wp + p * 8192 + n * 512);
    };

    // ---- barrier-free, LDS-free K-loop: A double-buffered 1 phase ahead;
    // counted vmcnt waits fall out of issue order (never drained to 0).
    issueA(0, 0);
    #pragma unroll
    for (int p = 0; p < NPH; p++) {
        if (p + 1 < NPH) issueA(p + 1, (p + 1) & 1);
        issueW(p);
        bf16x8 af[2];
        #pragma unroll
        for (int m = 0; m < 2; m++)
            af[m] = cvt8(av[p & 1][m][0], av[p & 1][m][1]);
        #pragma unroll
        for (int m = 0; m < 2; m++)
            #pragma unroll
            for (int n = 0; n < 4; n++)
                acc[m][n] = __builtin_amdgcn_mfma_f32_16x16x32_bf16(
                    af[m], __builtin_bit_cast(bf16x8, wv[n]), acc[m][n], 0, 0, 0);
    }

    // ---- dump Z (+bkv) to LDS bf16 (ZB swizzle); C/D: col=lane&15, row=(lane>>4)*4+j
    #pragma unroll
    for (int n = 0; n < 4; n++) {
        int col = wn * 64 + n * 16 + (lane & 15);
        float bk = bkv[col];
        #pragma unroll
        for (int m = 0; m < 2; m++) {
            #pragma unroll
            for (int j = 0; j < 4; j++) {
                int row = wm * 32 + m * 16 + (lane >> 4) * 4 + j;
                *(unsigned short*)(zsm + ZB(row, col)) =
                    __builtin_bit_cast(unsigned short, (__bf16)(acc[m][n][j] + bk));
            }
        }
    }
    __syncthreads();

    // ---- scores + softmax: waves 0..3 -> (b=wid>>1, h=wid&1); lane pair per n2
    if (wid < 2 * BPB) {
        int bl = wid >> 1, h = wid & 1;
        int n2 = lane >> 1, half = lane & 1;
        int np = h * 16 + (n2 >> 1);                  // Z row (mixed reshape)
        int rowZ = bl * NNBR + np;
        int cb = (n2 & 1) * 64 + half * 32;           // Z col base (K part)
        const float* q = &qres[bl][h * 64 + half * 32];
        float s = 0.f;
        #pragma unroll
        for (int j = 0; j < 4; j++) {
            short8 z8 = *(const short8*)(zsm + ZB(rowZ, cb + j * 8));
            #pragma unroll
            for (int e = 0; e < 8; e++)
                s += q[j * 8 + e] * bf2f((unsigned short)z8[e]);
        }
        s += __shfl_xor(s, 1);
        s *= 0.125f;  // HEAD_DIM^-0.5
        if (nbr_mask[(long)(b0 + bl) * NNBR + n2] == 0) s = -1e10f;
        float mx = s;
        #pragma unroll
        for (int off = 1; off < 64; off <<= 1) mx = fmaxf(mx, __shfl_xor(mx, off));
        float e = __expf(s - mx);
        float sum = e;
        #pragma unroll
        for (int off = 1; off < 64; off <<= 1) sum += __shfl_xor(sum, off);
        float p = e * 2.f / sum;   // each n2 counted twice in sum
        if (half == 0) Pband[bl][h][n2] = p;
    }
    __syncthreads();

    // ---- O = P @ V : one thread per (b, h*64+d)
    if (tid < BPB * ODIM) {
        int b = tid >> 7, c = tid & 127, h = c >> 6, d = c & 63;
        const float* P = Pband[b][h];
        float s = 0.f;
        #pragma unroll
        for (int n2 = 0; n2 < NNBR; n2++) {
            int np = h * 16 + (n2 >> 1);
            int col = ODIM + (n2 & 1) * 64 + d;       // V part
            s += P[n2] * bf2f(*(const unsigned short*)(zsm + ZB(b * NNBR + np, col)));
        }
        Obuf[b][c] = s;
    }
    __syncthreads();

    // ---- out proj (coalesced via WoT) + LayerNorm
    {
        int b = tid >> 7, c = tid & 127;
        float s = 0.f;
        if (tid < BPB * ODIM) {
            s = bo[c];
            const float* ob = Obuf[b];
            #pragma unroll 8
            for (int k = 0; k < ODIM; k++)
                s += ob[k] * bf2f(woT[k * 128 + c]);
        }
        float s1 = s, s2 = s * s;
        #pragma unroll
        for (int off = 1; off < 64; off <<= 1) {
            s1 += __shfl_xor(s1, off);
            s2 += __shfl_xor(s2, off);
        }
        if (wid < 2 * BPB && lane == 0) { red[wid][0] = s1; red[wid][1] = s2; }
        __syncthreads();
        if (tid < BPB * ODIM) {
            float t1 = red[b * 2][0] + red[b * 2 + 1][0];
            float t2 = red[b * 2][1] + red[b * 2 + 1][1];
            float mu  = t1 * (1.f / 128.f);
            float var = t2 * (1.f / 128.f) - mu * mu;
            float inv = rsqrtf(var + LN_EPS);
            out[(long)(b0 + b) * ODIM + c] = (s - mu) * inv * gamma[c] + beta[c];
        }
    }
}

extern "C" void kernel_launch(void* const* d_in, const int* in_sizes, int n_in,
                              void* d_out, int out_size, void* d_ws, size_t ws_size,
                              hipStream_t stream) {
    const float* node_feat = (const float*)d_in[0];
    const float* time_feat = (const float*)d_in[1];
    const float* edge_feat = (const float*)d_in[2];
    const float* nbr_node  = (const float*)d_in[3];
    const float* nbr_time  = (const float*)d_in[4];
    const int*   nbr_mask  = (const int*)d_in[5];
    const float* Wq   = (const float*)d_in[6];
    const float* bq   = (const float*)d_in[7];
    const float* Wkv  = (const float*)d_in[8];
    const float* bkv  = (const float*)d_in[9];
    const float* Wo   = (const float*)d_in[10];
    const float* bo   = (const float*)d_in[11];
    const float* gma  = (const float*)d_in[12];
    const float* bta  = (const float*)d_in[13];
    float* out = (float*)d_out;

    const int B = in_sizes[0] / NDIM;  // 8192

    // workspace layout
    char* ws = (char*)d_ws;
    float* Qbuf = (float*)ws;                                   // B*128*4 = 4 MB
    unsigned short* wfrag = (unsigned short*)(ws + (size_t)B * ODIM * 4);
    unsigned short* wqT   = wfrag + WFRAG_N;
    unsigned short* woT   = wqT + WQT_N;

    const int prep_total = WFRAG_N + WQT_N + WOT_N;
    prep_pack<<<dim3((prep_total + 255) / 256), dim3(256), 0, stream>>>(
        Wkv, Wq, Wo, wfrag, wqT, woT);
    q_proj<<<dim3(B / 8), dim3(256), 0, stream>>>(node_feat, time_feat, wqT, bq, Qbuf);
    ta_fused<<<dim3(B / BPB), dim3(512), 0, stream>>>(
        edge_feat, nbr_node, nbr_time, nbr_mask, Qbuf,
        wfrag, bkv, woT, bo, gma, bta, out);
}